// Round 12
// baseline (287.230 us; speedup 1.0000x reference)
//
#include <hip/hip_runtime.h>

typedef __attribute__((ext_vector_type(8))) short s16x8;
typedef __attribute__((ext_vector_type(8))) __bf16 bf16x8;
typedef __attribute__((ext_vector_type(4))) float f32x4;
typedef __attribute__((ext_vector_type(4))) unsigned short u16x4;
typedef __attribute__((ext_vector_type(4))) unsigned int u32x4;

__device__ __forceinline__ f32x4 mfma_bf16(s16x8 a, s16x8 b, f32x4 c) {
  return __builtin_amdgcn_mfma_f32_16x16x32_bf16(
      __builtin_bit_cast(bf16x8, a), __builtin_bit_cast(bf16x8, b), c, 0, 0, 0);
}

__device__ __forceinline__ unsigned short f2bf(float f) {
  unsigned int u = __builtin_bit_cast(unsigned int, f);
  unsigned int r = u + 0x7FFFu + ((u >> 16) & 1u);
  return (unsigned short)(r >> 16);
}

__device__ __forceinline__ unsigned int cvt_pk_bf16(float lo, float hi) {
  unsigned int d;
  asm volatile("v_cvt_pk_bf16_f32 %0, %1, %2" : "=v"(d) : "v"(lo), "v"(hi));
  return d;
}

// ---------------- fused fp32 -> bf16 convert for x and cond ----------------
__global__ __launch_bounds__(256) void convert_all(const float* __restrict__ x,
                                                   const float* __restrict__ cond,
                                                   unsigned short* __restrict__ xb,
                                                   unsigned short* __restrict__ condb) {
  int i = blockIdx.x * 256 + threadIdx.x;
  const float* in;
  unsigned short* out;
  if (i < 655360) {
    in = x; out = xb;
  } else {
    i -= 655360;
    if (i >= 1572864) return;
    in = cond; out = condb;
  }
  f32x4 v = ((const f32x4*)in)[i];
  u16x4 o;
  o[0] = f2bf(v[0]); o[1] = f2bf(v[1]); o[2] = f2bf(v[2]); o[3] = f2bf(v[3]);
  ((u16x4*)out)[i] = o;
}

// ---------- fused weight transpose+convert: fp32 [K][N] -> bf16 [N][K] -----
__global__ void transpose_all(const float* __restrict__ Wq, const float* __restrict__ Wk,
                              const float* __restrict__ Wv, const float* __restrict__ Wo,
                              unsigned short* __restrict__ WtQ, unsigned short* __restrict__ WtK,
                              unsigned short* __restrict__ WtV, unsigned short* __restrict__ WtO) {
  int id = blockIdx.x * 256 + threadIdx.x;
  const float* in;
  unsigned short* out;
  int K;
  if (id < 102400)      { in = Wq; out = WtQ; K = 320; }
  else if (id < 348160) { in = Wk; out = WtK; K = 768; id -= 102400; }
  else if (id < 593920) { in = Wv; out = WtV; K = 768; id -= 348160; }
  else if (id < 696320) { in = Wo; out = WtO; K = 320; id -= 593920; }
  else return;
  int k = id / 320, n = id - k * 320;
  out[(size_t)n * K + k] = f2bf(in[id]);
}

// ---------------- direct-global MFMA GEMM body, M=8192, N=320 --------------
// A [M][K] bf16, Wt [N][K] bf16. 64x64 block tile, 4 waves 2x2, each wave
// 32x32 via 2x2 16x16x32 fragments; depth-3 register pipeline over k.
// MODE 0: Q proj  -> bf16 dst[((b*8+h)*4096+s)*64 + d] * scale
// MODE 1: K proj  -> bf16 dst[((b*8+h)*4096+s)*64 + d]
// MODE 2: V proj  -> bf16 dst[((b*8+h)*48+d)*4096 + s']  (transposed,
//         s' = within-64-tile bit-rotated s so attn PV reads are b128)
// MODE 3: O proj  -> fp32 dst[m*320+n] + bias[n]
template <int MODE, int K>
__device__ __forceinline__ void gemm_body(
    const unsigned short* __restrict__ A, const unsigned short* __restrict__ Wt,
    void* __restrict__ dstv, const float* __restrict__ bias, float scale) {
  const int tid = threadIdx.x;
  const int l = tid & 63, w = tid >> 6;
  const int wm = w >> 1, wn = w & 1;
  const int lr = l & 15, lg = l >> 4;
  const int row0 = blockIdx.x * 64 + wm * 32;
  const int col0 = blockIdx.y * 64 + wn * 32;

  const unsigned short* Ap = A + (size_t)(row0 + lr) * K + lg * 8;
  const unsigned short* Bp = Wt + (size_t)(col0 + lr) * K + lg * 8;

  f32x4 acc[2][2];
#pragma unroll
  for (int i = 0; i < 2; i++)
#pragma unroll
    for (int j = 0; j < 2; j++) acc[i][j] = f32x4{0.f, 0.f, 0.f, 0.f};

  constexpr int NB = K / 32;
  constexpr int D = 3;  // pipeline depth
  s16x8 a0[D], a1[D], b0[D], b1[D];
#pragma unroll
  for (int i = 0; i < D - 1; i++) {
    const int k = i * 32;
    a0[i] = *(const s16x8*)(Ap + k);
    a1[i] = *(const s16x8*)(Ap + (size_t)16 * K + k);
    b0[i] = *(const s16x8*)(Bp + k);
    b1[i] = *(const s16x8*)(Bp + (size_t)16 * K + k);
  }

#pragma unroll
  for (int i = 0; i < NB; i++) {
    const int cur = i % D;
    if (i + D - 1 < NB) {
      const int k = (i + D - 1) * 32;
      const int sl = (i + D - 1) % D;
      a0[sl] = *(const s16x8*)(Ap + k);
      a1[sl] = *(const s16x8*)(Ap + (size_t)16 * K + k);
      b0[sl] = *(const s16x8*)(Bp + k);
      b1[sl] = *(const s16x8*)(Bp + (size_t)16 * K + k);
    }
    acc[0][0] = mfma_bf16(a0[cur], b0[cur], acc[0][0]);
    acc[0][1] = mfma_bf16(a0[cur], b1[cur], acc[0][1]);
    acc[1][0] = mfma_bf16(a1[cur], b0[cur], acc[1][0]);
    acc[1][1] = mfma_bf16(a1[cur], b1[cur], acc[1][1]);
  }

#pragma unroll
  for (int mf = 0; mf < 2; mf++)
#pragma unroll
    for (int nf = 0; nf < 2; nf++)
#pragma unroll
      for (int r = 0; r < 4; r++) {
        int m = row0 + mf * 16 + lg * 4 + r;
        int n = col0 + nf * 16 + lr;
        float v = acc[mf][nf][r];
        if (MODE == 0 || MODE == 1) {
          int b = m >> 12, s = m & 4095;
          int h = n / 40, d = n - h * 40;
          ((unsigned short*)dstv)[((size_t)(b * 8 + h) * 4096 + s) * 64 + d] =
              f2bf(v * scale);
        } else if (MODE == 2) {
          int b = m >> 12, s = m & 4095;
          int h = n / 40, d = n - h * 40;
          // within-64-tile perm: bits (c,hi,lg1,lg0,r1,r0) -> (c,lg1,lg0,hi,r1,r0)
          int sp = (s & ~63) | (s & 35) | ((s & 12) << 1) | ((s & 16) >> 2);
          ((unsigned short*)dstv)[((size_t)(b * 8 + h) * 48 + d) * 4096 + sp] = f2bf(v);
        } else {
          ((float*)dstv)[(size_t)m * 320 + n] = v + bias[n];
        }
      }
}

// fused Q/K/V projection: grid (128, 5, 3); z selects mode
__global__ __launch_bounds__(256) void qkv_proj(
    const unsigned short* __restrict__ xb, const unsigned short* __restrict__ condb,
    const unsigned short* __restrict__ WtQ, const unsigned short* __restrict__ WtK,
    const unsigned short* __restrict__ WtV, unsigned short* __restrict__ Qh,
    unsigned short* __restrict__ Kh, unsigned short* __restrict__ Vt, float qscale) {
  if (blockIdx.z == 0)      gemm_body<0, 320>(xb, WtQ, Qh, nullptr, qscale);
  else if (blockIdx.z == 1) gemm_body<1, 768>(condb, WtK, Kh, nullptr, 1.0f);
  else                      gemm_body<2, 768>(condb, WtV, Vt, nullptr, 1.0f);
}

__global__ __launch_bounds__(256) void o_proj(
    const unsigned short* __restrict__ AO, const unsigned short* __restrict__ WtO,
    float* __restrict__ out, const float* __restrict__ bias) {
  gemm_body<3, 320>(AO, WtO, out, bias, 1.0f);
}

// ---------------- flash attention, swapped-QK^T, 32 q-rows/wave ------------
// Qh [16][4096][64] (prescaled by scale*log2e, d>=40 zero)
// Kh [16][4096][64] (d>=40 zero), Vt [16][48][4096] (d>=40 zero, s-permuted)
// grid (16, 16); 512 threads = 8 waves; wave w owns q rows [qbase+32w, +32)
// as TWO 16-row subtiles (a,b) that SHARE every K/V fragment read -> DS
// traffic per useful FLOP halves vs r11 (DS was the measured bound).
__global__ __launch_bounds__(512) void attn_kernel(
    const unsigned short* __restrict__ Qh, const unsigned short* __restrict__ Kh,
    const unsigned short* __restrict__ Vt, unsigned short* __restrict__ AO) {
  __shared__ __align__(16) char kt[2][8192];   // K tile [64 kv][64 d], swizzled
  __shared__ __align__(16) char vts[2][6144];  // V^T tile [48 d][64 kv'], swizzled

  const int tid = threadIdx.x;
  const int l = tid & 63, w = tid >> 6;
  const int lr = l & 15, lg = l >> 4;
  const int bh = blockIdx.y;
  const int b = bh >> 3, h = bh & 7;
  const int qbase = blockIdx.x * 256;

  const unsigned short* Qp = Qh + ((size_t)bh * 4096 + qbase + w * 32) * 64;
  const unsigned short* Kp = Kh + (size_t)bh * 4096 * 64;
  const unsigned short* Vp = Vt + (size_t)bh * 48 * 4096;

  // staging coordinates (fixed per thread)
  const int srow = tid >> 3, sch = tid & 7;
  const bool hasv = (tid < 384);
  const int kofs = ((srow * 128 + sch * 16) ^ ((srow & 7) << 4));

  // Q as MFMA B-operand, two 16-row subtiles: B[n=q=lr][k=d]
  s16x8 qa0 = *(const s16x8*)(Qp + lr * 64 + lg * 8);
  s16x8 qa1 = *(const s16x8*)(Qp + lr * 64 + 32 + lg * 8);
  s16x8 qb0 = *(const s16x8*)(Qp + (16 + lr) * 64 + lg * 8);
  s16x8 qb1 = *(const s16x8*)(Qp + (16 + lr) * 64 + 32 + lg * 8);

  f32x4 Oa[3], Ob[3];  // O^T[d = nf*16 + lg*4 + r][q = lr]
#pragma unroll
  for (int nf = 0; nf < 3; nf++) {
    Oa[nf] = f32x4{0.f, 0.f, 0.f, 0.f};
    Ob[nf] = f32x4{0.f, 0.f, 0.f, 0.f};
  }
  float rma = -1e30f, rla = 0.f, rmb = -1e30f, rlb = 0.f;

  // prologue: stage tile 0 into buffer 0
  s16x8 kreg = *(const s16x8*)(Kp + (size_t)srow * 64 + sch * 8);
  s16x8 vreg;
  if (hasv) vreg = *(const s16x8*)(Vp + (size_t)srow * 4096 + sch * 8);
  *(s16x8*)(kt[0] + kofs) = kreg;
  if (hasv) *(s16x8*)(vts[0] + kofs) = vreg;
  __syncthreads();

  for (int t = 0; t < 64; ++t) {
    const int kb = t * 64;
    const int p = t & 1;
    const char* ktp = kt[p];
    const char* vtp = vts[p];

    // T14: issue next tile's global loads now; latency hides under compute
    if (t + 1 < 64) {
      kreg = *(const s16x8*)(Kp + (size_t)(kb + 64 + srow) * 64 + sch * 8);
      if (hasv) vreg = *(const s16x8*)(Vp + (size_t)srow * 4096 + kb + 64 + sch * 8);
    }

    // ---- QK^T (swapped): both subtiles share each K fragment read ----
    f32x4 sfa[4], sfb[4];
#pragma unroll
    for (int nf = 0; nf < 4; nf++) {
      sfa[nf] = f32x4{0.f, 0.f, 0.f, 0.f};
      sfb[nf] = f32x4{0.f, 0.f, 0.f, 0.f};
    }
    __builtin_amdgcn_s_setprio(1);
#pragma unroll
    for (int nf = 0; nf < 4; nf++) {
      int krow = nf * 16 + lr;
      s16x8 kf0 = *(const s16x8*)(ktp + ((krow * 128 + lg * 16) ^ ((krow & 7) << 4)));
      s16x8 kf1 = *(const s16x8*)(ktp + ((krow * 128 + 64 + lg * 16) ^ ((krow & 7) << 4)));
      sfa[nf] = mfma_bf16(kf0, qa0, sfa[nf]);
      sfa[nf] = mfma_bf16(kf1, qa1, sfa[nf]);
      sfb[nf] = mfma_bf16(kf0, qb0, sfb[nf]);
      sfb[nf] = mfma_bf16(kf1, qb1, sfb[nf]);
    }
    __builtin_amdgcn_s_setprio(0);

    // ---- online softmax, lane-local, subtile a ----
    unsigned int pka[4][2], pkb[4][2];
    {
      float tm = fmaxf(fmaxf(fmaxf(sfa[0][0], sfa[0][1]), fmaxf(sfa[0][2], sfa[0][3])),
                       fmaxf(fmaxf(sfa[1][0], sfa[1][1]), fmaxf(sfa[1][2], sfa[1][3])));
      tm = fmaxf(tm, fmaxf(fmaxf(fmaxf(sfa[2][0], sfa[2][1]), fmaxf(sfa[2][2], sfa[2][3])),
                           fmaxf(fmaxf(sfa[3][0], sfa[3][1]), fmaxf(sfa[3][2], sfa[3][3]))));
      tm = fmaxf(tm, __shfl_xor(tm, 16, 64));
      tm = fmaxf(tm, __shfl_xor(tm, 32, 64));
      if (!__all(tm <= rma)) {
        float mn = fmaxf(rma, tm);
        float al = __builtin_amdgcn_exp2f(rma - mn);
        rma = mn;
        rla *= al;
#pragma unroll
        for (int nf = 0; nf < 3; nf++)
#pragma unroll
          for (int r = 0; r < 4; r++) Oa[nf][r] *= al;
      }
      float ts = 0.f;
#pragma unroll
      for (int nf = 0; nf < 4; nf++) {
        float p0 = __builtin_amdgcn_exp2f(sfa[nf][0] - rma);
        float p1 = __builtin_amdgcn_exp2f(sfa[nf][1] - rma);
        float p2 = __builtin_amdgcn_exp2f(sfa[nf][2] - rma);
        float p3 = __builtin_amdgcn_exp2f(sfa[nf][3] - rma);
        ts += (p0 + p1) + (p2 + p3);
        pka[nf][0] = cvt_pk_bf16(p0, p1);
        pka[nf][1] = cvt_pk_bf16(p2, p3);
      }
      ts += __shfl_xor(ts, 16, 64);
      ts += __shfl_xor(ts, 32, 64);
      rla += ts;
    }
    // ---- subtile b ----
    {
      float tm = fmaxf(fmaxf(fmaxf(sfb[0][0], sfb[0][1]), fmaxf(sfb[0][2], sfb[0][3])),
                       fmaxf(fmaxf(sfb[1][0], sfb[1][1]), fmaxf(sfb[1][2], sfb[1][3])));
      tm = fmaxf(tm, fmaxf(fmaxf(fmaxf(sfb[2][0], sfb[2][1]), fmaxf(sfb[2][2], sfb[2][3])),
                           fmaxf(fmaxf(sfb[3][0], sfb[3][1]), fmaxf(sfb[3][2], sfb[3][3]))));
      tm = fmaxf(tm, __shfl_xor(tm, 16, 64));
      tm = fmaxf(tm, __shfl_xor(tm, 32, 64));
      if (!__all(tm <= rmb)) {
        float mn = fmaxf(rmb, tm);
        float al = __builtin_amdgcn_exp2f(rmb - mn);
        rmb = mn;
        rlb *= al;
#pragma unroll
        for (int nf = 0; nf < 3; nf++)
#pragma unroll
          for (int r = 0; r < 4; r++) Ob[nf][r] *= al;
      }
      float ts = 0.f;
#pragma unroll
      for (int nf = 0; nf < 4; nf++) {
        float p0 = __builtin_amdgcn_exp2f(sfb[nf][0] - rmb);
        float p1 = __builtin_amdgcn_exp2f(sfb[nf][1] - rmb);
        float p2 = __builtin_amdgcn_exp2f(sfb[nf][2] - rmb);
        float p3 = __builtin_amdgcn_exp2f(sfb[nf][3] - rmb);
        ts += (p0 + p1) + (p2 + p3);
        pkb[nf][0] = cvt_pk_bf16(p0, p1);
        pkb[nf][1] = cvt_pk_bf16(p2, p3);
      }
      ts += __shfl_xor(ts, 16, 64);
      ts += __shfl_xor(ts, 32, 64);
      rlb += ts;
    }

    // ---- PV: one V read feeds both subtiles' MFMAs ----
    __builtin_amdgcn_s_setprio(1);
#pragma unroll
    for (int c = 0; c < 2; c++) {
      u32x4 bua = {pka[2 * c][0], pka[2 * c][1], pka[2 * c + 1][0], pka[2 * c + 1][1]};
      u32x4 bub = {pkb[2 * c][0], pkb[2 * c][1], pkb[2 * c + 1][0], pkb[2 * c + 1][1]};
      s16x8 bfa = __builtin_bit_cast(s16x8, bua);
      s16x8 bfb = __builtin_bit_cast(s16x8, bub);
#pragma unroll
      for (int nf = 0; nf < 3; nf++) {
        int row = nf * 16 + lr;
        s16x8 afrag = *(const s16x8*)(
            vtp + ((row * 128 + c * 64 + lg * 16) ^ ((row & 7) << 4)));
        Oa[nf] = mfma_bf16(afrag, bfa, Oa[nf]);
        Ob[nf] = mfma_bf16(afrag, bfb, Ob[nf]);
      }
    }
    __builtin_amdgcn_s_setprio(0);

    // write next tile into the other buffer; single barrier per iter
    if (t + 1 < 64) {
      *(s16x8*)(kt[p ^ 1] + kofs) = kreg;
      if (hasv) *(s16x8*)(vts[p ^ 1] + kofs) = vreg;
      __syncthreads();
    }
  }

  // ---- epilogue: O^T/rl -> AO[b][s][h*40+d] ----
  const int qra = qbase + w * 32 + lr;
  float inva = 1.f / rla, invb = 1.f / rlb;
#pragma unroll
  for (int nf = 0; nf < 3; nf++) {
#pragma unroll
    for (int r = 0; r < 4; r++) {
      int d = nf * 16 + lg * 4 + r;
      if (d < 40) {
        AO[((size_t)(b * 4096 + qra)) * 320 + h * 40 + d] = f2bf(Oa[nf][r] * inva);
        AO[((size_t)(b * 4096 + qra + 16)) * 320 + h * 40 + d] = f2bf(Ob[nf][r] * invb);
      }
    }
  }
}

// ---------------------------------------------------------------------------
extern "C" void kernel_launch(void* const* d_in, const int* in_sizes, int n_in,
                              void* d_out, int out_size, void* d_ws,
                              size_t ws_size, hipStream_t stream) {
  const float* x    = (const float*)d_in[0];
  const float* cond = (const float*)d_in[1];
  const float* Wq   = (const float*)d_in[2];
  const float* Wk   = (const float*)d_in[3];
  const float* Wv   = (const float*)d_in[4];
  const float* Wo   = (const float*)d_in[5];
  const float* bo   = (const float*)d_in[6];

  char* ws = (char*)d_ws;
  unsigned short* xb    = (unsigned short*)(ws + 0);          // 8192*320*2   = 5,242,880
  unsigned short* condb = (unsigned short*)(ws + 5242880);    // 8192*768*2   = 12,582,912
  unsigned short* WtQ   = (unsigned short*)(ws + 17825792);   // 320*320*2    = 204,800
  unsigned short* WtK   = (unsigned short*)(ws + 18030592);   // 768*320*2    = 491,520
  unsigned short* WtV   = (unsigned short*)(ws + 18522112);   // 768*320*2    = 491,520
  unsigned short* WtO   = (unsigned short*)(ws + 19013632);   // 320*320*2    = 204,800
  unsigned short* AO    = (unsigned short*)(ws + 19218432);   // 8192*320*2   = 5,242,880
  unsigned short* Qh    = (unsigned short*)(ws + 24461312);   // 16*4096*64*2 = 8,388,608
  unsigned short* Kh    = (unsigned short*)(ws + 32849920);   // 16*4096*64*2 = 8,388,608
  unsigned short* Vt    = (unsigned short*)(ws + 41238528);   // 16*48*4096*2 = 6,291,456
  // total = 47,529,984 bytes

  // zero padded Q/K/V buffers (d>=40 pads must be 0 for MFMA correctness)
  hipMemsetAsync(Qh, 0, 23068672, stream);

  convert_all<<<dim3(8704), 256, 0, stream>>>(x, cond, xb, condb);
  transpose_all<<<dim3(2720), 256, 0, stream>>>(Wq, Wk, Wv, Wo, WtQ, WtK, WtV, WtO);

  const float qscale = 1.44269504088896f / sqrtf(40.0f);  // log2(e)/sqrt(Dh)

  qkv_proj<<<dim3(128, 5, 3), 256, 0, stream>>>(xb, condb, WtQ, WtK, WtV, Qh, Kh, Vt,
                                                qscale);
  attn_kernel<<<dim3(16, 16), 512, 0, stream>>>(Qh, Kh, Vt, AO);
  o_proj<<<dim3(128, 5), 256, 0, stream>>>(AO, WtO, (float*)d_out, bo);
}